// Round 9
// baseline (200.436 us; speedup 1.0000x reference)
//
#include <hip/hip_runtime.h>
#include <math.h>

#define LN_EPS 1e-5f

// N=512, L=256, P=64
// ws layout (floats):
//   proj (lg lv rg rv) @ 0       262144
//   left   @ 262144   65536
//   right  @ 327680   65536
//   Aw     @ 393216   32768
//   Bw     @ 425984   32768
//   rsrm   @ 458752   524288    float2 per (i,j): {rs_s, rs_s*mu_s}
//   cs     @ 983040   128
//   act    @ 983168   513 ints  (act[0]=count, act[1..] = active indices)

typedef __bf16 bf16x8 __attribute__((ext_vector_type(8)));
typedef float f32x16 __attribute__((ext_vector_type(16)));

__device__ __forceinline__ float gelu_f(float x) {
    float x2 = x * x;
    float e = __builtin_amdgcn_exp2f(x * fmaf(0.10294423f, x2, 2.3022079f));
    float r = __builtin_amdgcn_rcpf(e + 1.0f);
    return fmaf(-x, r, x);
}

// ---------- kA: LN(local) @ W_*  +  (bx==64): compaction / zero left+right ----------
__global__ __launch_bounds__(256) void kA(
    const float* __restrict__ loc,
    const float* __restrict__ Wlg, const float* __restrict__ Wlv,
    const float* __restrict__ Wrg, const float* __restrict__ Wrv,
    float* __restrict__ proj, const int* __restrict__ mask,
    int* __restrict__ act, float* __restrict__ left, float* __restrict__ right) {
    const int t = threadIdx.x;
    if (blockIdx.x == 64) {
        if (blockIdx.y == 1) {          // zero left
            float4 z = {0.f, 0.f, 0.f, 0.f};
            for (int idx = t; idx < 16384; idx += 256) ((float4*)left)[idx] = z;
        } else if (blockIdx.y == 2) {   // zero right
            float4 z = {0.f, 0.f, 0.f, 0.f};
            for (int idx = t; idx < 16384; idx += 256) ((float4*)right)[idx] = z;
        } else if (blockIdx.y == 0) {   // compact active indices
            __shared__ int cnt_sh[8];
            const int lane = t & 63, wv = t >> 6;
            int msave[2];
            unsigned long long bsave[2];
#pragma unroll
            for (int ch = 0; ch < 2; ++ch) {
                int m = (mask[ch * 256 + t] != 0);
                unsigned long long b = __ballot(m);
                if (lane == 0) cnt_sh[ch * 4 + wv] = __popcll(b);
                msave[ch] = m;
                bsave[ch] = b;
            }
            __syncthreads();
#pragma unroll
            for (int ch = 0; ch < 2; ++ch) {
                int base = 0;
                for (int u = 0; u < ch * 4 + wv; ++u) base += cnt_sh[u];
                int pos = base + __popcll(bsave[ch] & ((1ull << lane) - 1ull));
                if (msave[ch]) act[1 + pos] = ch * 256 + t;
            }
            if (t == 0) {
                int ctot = 0;
                for (int u = 0; u < 8; ++u) ctot += cnt_sh[u];
                act[0] = ctot;
            }
        }
        return;
    }
    __shared__ float ln_sh[8][260];
    __shared__ float red_sh[128][9];
    const int i0 = blockIdx.x * 8;
    const int mat = blockIdx.y;
    const float* __restrict__ W = (mat == 0) ? Wlg : (mat == 1) ? Wlv
                                 : (mat == 2) ? Wrg : Wrv;
    {
        int row = t >> 5, l32 = t & 31;
        const float4* src = (const float4*)(loc + (i0 + row) * 256);
        float4 v0 = src[l32 * 2];
        float4 v1 = src[l32 * 2 + 1];
        float s = (v0.x + v0.y) + (v0.z + v0.w) + (v1.x + v1.y) + (v1.z + v1.w);
        float ss = v0.x * v0.x + v0.y * v0.y + v0.z * v0.z + v0.w * v0.w +
                   v1.x * v1.x + v1.y * v1.y + v1.z * v1.z + v1.w * v1.w;
#pragma unroll
        for (int off = 1; off < 32; off <<= 1) {
            s += __shfl_xor(s, off);
            ss += __shfl_xor(ss, off);
        }
        float mu = s * (1.f / 256.f);
        float rs = rsqrtf(ss * (1.f / 256.f) - mu * mu + LN_EPS);
        float4 o0, o1;
        o0.x = (v0.x - mu) * rs; o0.y = (v0.y - mu) * rs;
        o0.z = (v0.z - mu) * rs; o0.w = (v0.w - mu) * rs;
        o1.x = (v1.x - mu) * rs; o1.y = (v1.y - mu) * rs;
        o1.z = (v1.z - mu) * rs; o1.w = (v1.w - mu) * rs;
        *(float4*)&ln_sh[row][l32 * 8] = o0;
        *(float4*)&ln_sh[row][l32 * 8 + 4] = o1;
    }
    __syncthreads();

    const int n = t & 127;
    const int kh = t >> 7;
    float acc[8] = {0.f, 0.f, 0.f, 0.f, 0.f, 0.f, 0.f, 0.f};
#pragma unroll 2
    for (int c = 0; c < 32; ++c) {
        const int kc = kh * 128 + c * 4;
        float w0 = W[(kc + 0) * 128 + n];
        float w1 = W[(kc + 1) * 128 + n];
        float w2 = W[(kc + 2) * 128 + n];
        float w3 = W[(kc + 3) * 128 + n];
#pragma unroll
        for (int r = 0; r < 8; ++r) {
            float4 l4 = *(const float4*)&ln_sh[r][kc];
            acc[r] += l4.x * w0 + l4.y * w1 + l4.z * w2 + l4.w * w3;
        }
    }
    if (kh == 1) {
#pragma unroll
        for (int r = 0; r < 8; ++r) red_sh[n][r] = acc[r];
    }
    __syncthreads();
    if (kh == 0) {
#pragma unroll
        for (int r = 0; r < 8; ++r)
            proj[mat * 65536 + (i0 + r) * 128 + n] = acc[r] + red_sh[n][r];
    }
}

// ---------- kB: compacted i,j; dual-accumulator MFMA; dbuf staging ----------
#define KB_TI 4
__global__ __launch_bounds__(256) void kB(
    const float* __restrict__ pair, const int* __restrict__ act,
    const float* __restrict__ Wg, const float* __restrict__ Wv,
    const float* __restrict__ lg, const float* __restrict__ lv,
    const float* __restrict__ rg, const float* __restrict__ rv,
    float* __restrict__ left, float* __restrict__ right) {
    __shared__ __bf16 A_sh[2][32][72];
    __shared__ int ji_sh[32];
    __shared__ int ii_sh[KB_TI];

    const int cnt = act[0];
    const int j0 = blockIdx.x * 32;
    const int ibase = blockIdx.y * KB_TI;
    if (j0 >= cnt || ibase >= cnt) return;
    const int nact = min(KB_TI, cnt - ibase);

    const int t = threadIdx.x;
    const int lane = t & 63;
    const int w = t >> 6;
    const int c = lane & 31;
    const int half = lane >> 5;
    const int n = w * 32 + c;

    if (t < 32) ji_sh[t] = act[1 + min(j0 + t, cnt - 1)];
    if (t >= 64 && t < 64 + KB_TI) ii_sh[t - 64] = act[1 + min(ibase + (t - 64), cnt - 1)];
    __syncthreads();

    bf16x8 bg[4], bv[4];
#pragma unroll
    for (int kt = 0; kt < 4; ++kt) {
        bf16x8 vg, vv;
#pragma unroll
        for (int e = 0; e < 8; ++e) {
            int kr = kt * 16 + half * 8 + e;
            vg[e] = (__bf16)Wg[kr * 128 + n];
            vv[e] = (__bf16)Wv[kr * 128 + n];
        }
        bg[kt] = vg; bv[kt] = vv;
    }

    float lvr[16], rgr[16];
    unsigned jmask = 0;
#pragma unroll
    for (int r = 0; r < 16; ++r) {
        int m = 4 * half + (r & 3) + 8 * (r >> 2);
        int j = ji_sh[m];
        lvr[r] = lv[j * 128 + n];
        rgr[r] = rg[j * 128 + n];
        if (j0 + m < cnt) jmask |= (1u << r);
    }

    const int srow = t >> 3;
    const int kseg = (t & 7) * 8;
    float4 p0, p1;
    float plg, prv;
    {
        int iF = ii_sh[0];
        const float* src = pair + ((size_t)iF * 512 + ji_sh[srow]) * 64 + kseg;
        p0 = *(const float4*)src;
        p1 = *(const float4*)(src + 4);
        plg = lg[iF * 128 + n];
        prv = rv[iF * 128 + n];
    }

    auto lnwrite = [&](int buf) {
        float s = (p0.x + p0.y) + (p0.z + p0.w) + (p1.x + p1.y) + (p1.z + p1.w);
        float ss = p0.x * p0.x + p0.y * p0.y + p0.z * p0.z + p0.w * p0.w +
                   p1.x * p1.x + p1.y * p1.y + p1.z * p1.z + p1.w * p1.w;
        s += __shfl_xor(s, 1); ss += __shfl_xor(ss, 1);
        s += __shfl_xor(s, 2); ss += __shfl_xor(ss, 2);
        s += __shfl_xor(s, 4); ss += __shfl_xor(ss, 4);
        float mu = s * (1.f / 64.f);
        float rs = rsqrtf(ss * (1.f / 64.f) - mu * mu + LN_EPS);
        bf16x8 o;
        o[0] = (__bf16)((p0.x - mu) * rs); o[1] = (__bf16)((p0.y - mu) * rs);
        o[2] = (__bf16)((p0.z - mu) * rs); o[3] = (__bf16)((p0.w - mu) * rs);
        o[4] = (__bf16)((p1.x - mu) * rs); o[5] = (__bf16)((p1.y - mu) * rs);
        o[6] = (__bf16)((p1.z - mu) * rs); o[7] = (__bf16)((p1.w - mu) * rs);
        *(bf16x8*)&A_sh[buf][srow][kseg] = o;
    };
    lnwrite(0);
    __syncthreads();

    float racc[16];
#pragma unroll
    for (int r = 0; r < 16; ++r) racc[r] = 0.f;

    for (int ii = 0; ii < nact; ++ii) {
        const int i = ii_sh[ii];
        const float lgi = plg;
        const float rvi = prv;
        if (ii + 1 < nact) {
            int iF = ii_sh[ii + 1];
            const float* src = pair + ((size_t)iF * 512 + ji_sh[srow]) * 64 + kseg;
            p0 = *(const float4*)src;
            p1 = *(const float4*)(src + 4);
            plg = lg[iF * 128 + n];
            prv = rv[iF * 128 + n];
        }

        f32x16 ag = {}; f32x16 av = {};
#pragma unroll
        for (int kt = 0; kt < 4; ++kt) {
            bf16x8 af = *(const bf16x8*)&A_sh[ii & 1][c][kt * 16 + half * 8];
            ag = __builtin_amdgcn_mfma_f32_32x32x16_bf16(af, bg[kt], ag, 0, 0, 0);
            av = __builtin_amdgcn_mfma_f32_32x32x16_bf16(af, bv[kt], av, 0, 0, 0);
        }

        float lsum = 0.f;
#pragma unroll
        for (int r = 0; r < 16; ++r) {
            float pg = ag[r], pv = av[r];
            float lres = gelu_f(lgi + pg) * (lvr[r] + pv);
            float rres = gelu_f(rgr[r] + pg) * (rvi + pv);
            lsum += ((jmask >> r) & 1) ? lres : 0.f;
            racc[r] += rres;
        }
        float tot = lsum + __shfl_xor(lsum, 32);
        if (lane < 32) atomicAdd(&left[i * 128 + n], tot);

        if (ii + 1 < nact) lnwrite((ii + 1) & 1);
        __syncthreads();
    }

#pragma unroll
    for (int r = 0; r < 16; ++r) {
        if ((jmask >> r) & 1) {
            int m = 4 * half + (r & 3) + 8 * (r >> 2);
            atomicAdd(&right[ji_sh[m] * 128 + n], racc[r]);
        }
    }
}

// ---------- kD: kD1 (A/B proj + colsums) and kD2 (C = L@R^T, fused LN-stat precompute) ----------
__global__ __launch_bounds__(256) void kD(
    const float* __restrict__ left, const float* __restrict__ right,
    const float* __restrict__ W_out,
    float* __restrict__ Aw, float* __restrict__ Bw,
    float* __restrict__ rsrm, float* __restrict__ cs) {
    const int bx = blockIdx.x;
    const int t = threadIdx.x;
    if (bx < 256) {   // --- kD2 tile ---
        __shared__ float l_sh[32][68];
        __shared__ float r_sh[32][68];
        const int tx = t & 15, ty = t >> 4;
        const int i0 = (bx & 15) * 32, j0 = (bx >> 4) * 32;
        float acc00 = 0.f, acc01 = 0.f, acc10 = 0.f, acc11 = 0.f;
        float sL0 = 0.f, ssL0 = 0.f, sL1 = 0.f, ssL1 = 0.f;
        float sR0 = 0.f, ssR0 = 0.f, sR1 = 0.f, ssR1 = 0.f;
        for (int kc = 0; kc < 128; kc += 64) {
            __syncthreads();
#pragma unroll
            for (int u = 0; u < 2; ++u) {
                int fi = t + u * 256;
                int row = fi >> 4, kq = (fi & 15) * 4;
                float4 lv4 = *(const float4*)(left + (i0 + row) * 128 + kc + kq);
                float4 rv4 = *(const float4*)(right + (j0 + row) * 128 + kc + kq);
                *(float4*)&l_sh[row][kq] = lv4;
                *(float4*)&r_sh[row][kq] = rv4;
            }
            __syncthreads();
#pragma unroll
            for (int k4 = 0; k4 < 64; k4 += 4) {
                float4 l0 = *(const float4*)&l_sh[ty * 2 + 0][k4];
                float4 l1 = *(const float4*)&l_sh[ty * 2 + 1][k4];
                float4 r0 = *(const float4*)&r_sh[tx * 2 + 0][k4];
                float4 r1 = *(const float4*)&r_sh[tx * 2 + 1][k4];
                acc00 += l0.x * r0.x + l0.y * r0.y + l0.z * r0.z + l0.w * r0.w;
                acc01 += l0.x * r1.x + l0.y * r1.y + l0.z * r1.z + l0.w * r1.w;
                acc10 += l1.x * r0.x + l1.y * r0.y + l1.z * r0.z + l1.w * r0.w;
                acc11 += l1.x * r1.x + l1.y * r1.y + l1.z * r1.z + l1.w * r1.w;
                sL0 += (l0.x + l0.y) + (l0.z + l0.w);
                ssL0 += l0.x * l0.x + l0.y * l0.y + l0.z * l0.z + l0.w * l0.w;
                sL1 += (l1.x + l1.y) + (l1.z + l1.w);
                ssL1 += l1.x * l1.x + l1.y * l1.y + l1.z * l1.z + l1.w * l1.w;
                sR0 += (r0.x + r0.y) + (r0.z + r0.w);
                ssR0 += r0.x * r0.x + r0.y * r0.y + r0.z * r0.z + r0.w * r0.w;
                sR1 += (r1.x + r1.y) + (r1.z + r1.w);
                ssR1 += r1.x * r1.x + r1.y * r1.y + r1.z * r1.z + r1.w * r1.w;
            }
        }
        {
            float sLa[2] = {sL0, sL1}, ssLa[2] = {ssL0, ssL1};
            float sRb[2] = {sR0, sR1}, ssRb[2] = {ssR0, ssR1};
            float accv[2][2] = {{acc00, acc01}, {acc10, acc11}};
#pragma unroll
            for (int a = 0; a < 2; ++a) {
#pragma unroll
                for (int b = 0; b < 2; ++b) {
                    float mu = (sLa[a] + sRb[b]) * (1.f / 128.f);
                    float var = fmaf(-mu, mu,
                                     (ssLa[a] + 2.f * accv[a][b] + ssRb[b]) * (1.f / 128.f));
                    float rs = rsqrtf(var + LN_EPS);
                    size_t idx = (size_t)(i0 + ty * 2 + a) * 512 + (j0 + tx * 2 + b);
                    float2 v; v.x = rs; v.y = rs * mu;
                    ((float2*)rsrm)[idx] = v;
                }
            }
        }
    } else {          // --- kD1: two (r, which) jobs per block ---
        const int id = bx - 256;            // 0..511
        const int which = id >> 8;
        const int sub = t >> 7;
        const int tt = t & 127;
        const int r = (id & 255) * 2 + sub;
        const float* src = which ? right : left;
        __shared__ float row_sh[2][128];
        row_sh[sub][tt] = src[r * 128 + tt];
        __syncthreads();
        if (tt < 64) {
            float a = 0.f;
            const float* W2 = W_out + 64 * 64;
#pragma unroll 8
            for (int m = 0; m < 128; ++m) a += row_sh[sub][m] * W2[m * 64 + tt];
            (which ? Bw : Aw)[r * 64 + tt] = a;
        }
        if (id == 0 && t < 64) {
            float c0 = 0.f, c1 = 0.f;
            for (int k = 0; k < 64; ++k) c0 += W_out[k * 64 + t];
            for (int m = 0; m < 128; ++m) c1 += W_out[(64 + m) * 64 + t];
            cs[t] = c0;
            cs[64 + t] = c1;
        }
    }
}

// ---------- kC: 4-deep i-pipelined; stats one-i-ahead; LDS-staged rsrm tile ----------
// R8 counters: 40 us at 2.56 TB/s, all pipes <20% — remaining stall is the
// epilogue's 16 scattered 8B broadcast loads of rsrm per body (not covered by
// the prefetch pipeline). Fix: block's rsrm need is a 4x64 float2 tile (2 KB);
// stage it coalesced into LDS once at block start (+1 barrier), epilogue reads
// LDS (uniform addr per half-wave -> broadcast, ~60cy). Aw[i0..3] also hoisted.
__global__ __launch_bounds__(256) void kC(
    const float* __restrict__ pair, const float* __restrict__ Wout,
    const float* __restrict__ Aw, const float* __restrict__ Bw,
    const float* __restrict__ rsrm,
    const float* __restrict__ cs, float* __restrict__ out) {
    __shared__ float2 rsrm_sh[4][64];
    const int t = threadIdx.x;
    const int lane = t & 63;
    const int w = t >> 6;
    const int c = lane & 31;
    const int half = lane >> 5;
    const int i0 = blockIdx.x * 4;
    const int j0 = blockIdx.y * 64;
    const int mt = w & 1;
    const int nt = w >> 1;
    const int n = nt * 32 + c;
    const int jrow = j0 + mt * 32 + c;

    const float* __restrict__ abase = pair + ((size_t)i0 * 512 + jrow) * 64 + half * 8;

    float4 va[8], vb[8];
#pragma unroll
    for (int kt = 0; kt < 4; ++kt) {             // issue i0's pair loads first
        va[2 * kt] = *(const float4*)(abase + kt * 16);
        va[2 * kt + 1] = *(const float4*)(abase + kt * 16 + 4);
    }

    // coalesced stage of the block's rsrm tile: thread t -> (i = t>>6, jj = t&63)
    rsrm_sh[t >> 6][t & 63] =
        ((const float2*)rsrm)[(size_t)(i0 + (t >> 6)) * 512 + j0 + (t & 63)];

    bf16x8 bo[4];                                 // i-invariant: Wout fragments
#pragma unroll
    for (int kt = 0; kt < 4; ++kt) {
        bf16x8 bb;
#pragma unroll
        for (int e = 0; e < 8; ++e)
            bb[e] = (__bf16)Wout[(kt * 16 + half * 8 + e) * 64 + n];
        bo[kt] = bb;
    }
    float Bv[16];                                 // i-invariant: Bw values
#pragma unroll
    for (int r = 0; r < 16; ++r) {
        int jp = j0 + mt * 32 + 4 * half + (r & 3) + 8 * (r >> 2);
        Bv[r] = Bw[jp * 64 + n];
    }
    float Awr[4];                                 // hoisted Aw for i0..i0+3
#pragma unroll
    for (int u = 0; u < 4; ++u) Awr[u] = Aw[(i0 + u) * 64 + n];
    const float cs1n = cs[64 + n];

    auto stats = [&](float4 (&buf)[8], float& rs_o, float& nmr_o) {
        float s = 0.f, ss = 0.f;
#pragma unroll
        for (int u = 0; u < 8; ++u) {
            s += (buf[u].x + buf[u].y) + (buf[u].z + buf[u].w);
            ss += buf[u].x * buf[u].x + buf[u].y * buf[u].y +
                  buf[u].z * buf[u].z + buf[u].w * buf[u].w;
        }
        s += __shfl_xor(s, 32);
        ss += __shfl_xor(ss, 32);
        float mu = s * (1.f / 64.f);
        float rs = rsqrtf(ss * (1.f / 64.f) - mu * mu + LN_EPS);
        rs_o = rs;
        nmr_o = -mu * rs;
    };

    float rsA, nmrA, rsB, nmrB;
    stats(va, rsA, nmrA);
    __syncthreads();                              // rsrm_sh ready

    auto body = [&](float4 (&cur)[8], float4 (&nxt)[8], int ii,
                    float rs_c, float nmr_c, float& rs_n, float& nmr_n) {
        if (ii < 3) {                             // prefetch next i
            const float* src = abase + (size_t)(ii + 1) * 512 * 64;
#pragma unroll
            for (int kt = 0; kt < 4; ++kt) {
                nxt[2 * kt] = *(const float4*)(src + kt * 16);
                nxt[2 * kt + 1] = *(const float4*)(src + kt * 16 + 4);
            }
        }
        const int i = i0 + ii;
        const float A_in = Awr[ii];

        f32x16 acc = {};
#pragma unroll
        for (int kt = 0; kt < 4; ++kt) {
            bf16x8 af;
#pragma unroll
            for (int u = 0; u < 2; ++u) {
                float4 vv = cur[2 * kt + u];
                af[u * 4 + 0] = (__bf16)fmaf(vv.x, rs_c, nmr_c);
                af[u * 4 + 1] = (__bf16)fmaf(vv.y, rs_c, nmr_c);
                af[u * 4 + 2] = (__bf16)fmaf(vv.z, rs_c, nmr_c);
                af[u * 4 + 3] = (__bf16)fmaf(vv.w, rs_c, nmr_c);
            }
            acc = __builtin_amdgcn_mfma_f32_32x32x16_bf16(af, bo[kt], acc, 0, 0, 0);
        }

        if (ii < 3) stats(nxt, rs_n, nmr_n);      // hides under MFMA latency

#pragma unroll
        for (int r = 0; r < 16; ++r) {
            int jl = mt * 32 + 4 * half + (r & 3) + 8 * (r >> 2);
            float2 rr = rsrm_sh[ii][jl];
            out[((size_t)i * 512 + j0 + jl) * 64 + n] =
                fmaf(rr.x, A_in + Bv[r], fmaf(-rr.y, cs1n, acc[r]));
        }
    };
    body(va, vb, 0, rsA, nmrA, rsB, nmrB);
    body(vb, va, 1, rsB, nmrB, rsA, nmrA);
    body(va, vb, 2, rsA, nmrA, rsB, nmrB);
    body(vb, va, 3, rsB, nmrB, rsA, nmrA);
}

extern "C" void kernel_launch(void* const* d_in, const int* in_sizes, int n_in,
                              void* d_out, int out_size, void* d_ws, size_t ws_size,
                              hipStream_t stream) {
    const float* loc  = (const float*)d_in[0];
    const float* pair = (const float*)d_in[1];
    const int*   mask = (const int*)d_in[2];
    const float* Wpg  = (const float*)d_in[3];
    const float* Wpv  = (const float*)d_in[4];
    const float* Wlg  = (const float*)d_in[5];
    const float* Wlv  = (const float*)d_in[6];
    const float* Wrg  = (const float*)d_in[7];
    const float* Wrv  = (const float*)d_in[8];
    const float* Wout = (const float*)d_in[9];
    float* out = (float*)d_out;
    float* ws = (float*)d_ws;

    float* proj   = ws;             // lg lv rg rv
    float* left   = ws + 262144;
    float* right  = ws + 327680;
    float* Aw     = ws + 393216;
    float* Bw     = ws + 425984;
    float* rsrm   = ws + 458752;    // float2[512*512]: {rs_s, rs_s*mu_s}
    float* cs     = ws + 983040;
    int*   act    = (int*)(ws + 983168);

    kA<<<dim3(65, 4), 256, 0, stream>>>(loc, Wlg, Wlv, Wrg, Wrv, proj,
                                        mask, act, left, right);
    kB<<<dim3(16, 128), 256, 0, stream>>>(pair, act, Wpg, Wpv,
                                          proj, proj + 65536, proj + 131072,
                                          proj + 196608, left, right);
    kD<<<768, 256, 0, stream>>>(left, right, Wout, Aw, Bw, rsrm, cs);
    kC<<<dim3(128, 8), 256, 0, stream>>>(pair, Wout, Aw, Bw, rsrm, cs, out);
}

// Round 11
// 194.370 us; speedup vs baseline: 1.0312x; 1.0312x over previous
//
#include <hip/hip_runtime.h>
#include <math.h>

#define LN_EPS 1e-5f

// N=512, L=256, P=64
// ws layout (floats):
//   proj (lg lv rg rv) @ 0       262144
//   left   @ 262144   65536
//   right  @ 327680   65536
//   Aw     @ 393216   32768
//   Bw     @ 425984   32768
//   rsrm   @ 458752   524288    float2 per (i,j): {rs_s, rs_s*mu_s}
//   cs     @ 983040   128
//   act    @ 983168   513 ints  (act[0]=count, act[1..] = active indices)

typedef __bf16 bf16x8 __attribute__((ext_vector_type(8)));
typedef float f32x16 __attribute__((ext_vector_type(16)));

__device__ __forceinline__ float gelu_f(float x) {
    float x2 = x * x;
    float e = __builtin_amdgcn_exp2f(x * fmaf(0.10294423f, x2, 2.3022079f));
    float r = __builtin_amdgcn_rcpf(e + 1.0f);
    return fmaf(-x, r, x);
}

// async global->LDS, 16 bytes per lane (lane's 16B lands at lds_base + lane*16)
__device__ __forceinline__ void gload_lds16(const float* g, float* lds_base) {
    __builtin_amdgcn_global_load_lds(
        (const __attribute__((address_space(1))) unsigned int*)g,
        (__attribute__((address_space(3))) unsigned int*)lds_base,
        16, 0, 0);
}

// ---------- kA: LN(local) @ W_*  +  (bx==64): compaction / zero left+right ----------
__global__ __launch_bounds__(256) void kA(
    const float* __restrict__ loc,
    const float* __restrict__ Wlg, const float* __restrict__ Wlv,
    const float* __restrict__ Wrg, const float* __restrict__ Wrv,
    float* __restrict__ proj, const int* __restrict__ mask,
    int* __restrict__ act, float* __restrict__ left, float* __restrict__ right) {
    const int t = threadIdx.x;
    if (blockIdx.x == 64) {
        if (blockIdx.y == 1) {          // zero left
            float4 z = {0.f, 0.f, 0.f, 0.f};
            for (int idx = t; idx < 16384; idx += 256) ((float4*)left)[idx] = z;
        } else if (blockIdx.y == 2) {   // zero right
            float4 z = {0.f, 0.f, 0.f, 0.f};
            for (int idx = t; idx < 16384; idx += 256) ((float4*)right)[idx] = z;
        } else if (blockIdx.y == 0) {   // compact active indices
            __shared__ int cnt_sh[8];
            const int lane = t & 63, wv = t >> 6;
            int msave[2];
            unsigned long long bsave[2];
#pragma unroll
            for (int ch = 0; ch < 2; ++ch) {
                int m = (mask[ch * 256 + t] != 0);
                unsigned long long b = __ballot(m);
                if (lane == 0) cnt_sh[ch * 4 + wv] = __popcll(b);
                msave[ch] = m;
                bsave[ch] = b;
            }
            __syncthreads();
#pragma unroll
            for (int ch = 0; ch < 2; ++ch) {
                int base = 0;
                for (int u = 0; u < ch * 4 + wv; ++u) base += cnt_sh[u];
                int pos = base + __popcll(bsave[ch] & ((1ull << lane) - 1ull));
                if (msave[ch]) act[1 + pos] = ch * 256 + t;
            }
            if (t == 0) {
                int ctot = 0;
                for (int u = 0; u < 8; ++u) ctot += cnt_sh[u];
                act[0] = ctot;
            }
        }
        return;
    }
    __shared__ float ln_sh[8][260];
    __shared__ float red_sh[128][9];
    const int i0 = blockIdx.x * 8;
    const int mat = blockIdx.y;
    const float* __restrict__ W = (mat == 0) ? Wlg : (mat == 1) ? Wlv
                                 : (mat == 2) ? Wrg : Wrv;
    {
        int row = t >> 5, l32 = t & 31;
        const float4* src = (const float4*)(loc + (i0 + row) * 256);
        float4 v0 = src[l32 * 2];
        float4 v1 = src[l32 * 2 + 1];
        float s = (v0.x + v0.y) + (v0.z + v0.w) + (v1.x + v1.y) + (v1.z + v1.w);
        float ss = v0.x * v0.x + v0.y * v0.y + v0.z * v0.z + v0.w * v0.w +
                   v1.x * v1.x + v1.y * v1.y + v1.z * v1.z + v1.w * v1.w;
#pragma unroll
        for (int off = 1; off < 32; off <<= 1) {
            s += __shfl_xor(s, off);
            ss += __shfl_xor(ss, off);
        }
        float mu = s * (1.f / 256.f);
        float rs = rsqrtf(ss * (1.f / 256.f) - mu * mu + LN_EPS);
        float4 o0, o1;
        o0.x = (v0.x - mu) * rs; o0.y = (v0.y - mu) * rs;
        o0.z = (v0.z - mu) * rs; o0.w = (v0.w - mu) * rs;
        o1.x = (v1.x - mu) * rs; o1.y = (v1.y - mu) * rs;
        o1.z = (v1.z - mu) * rs; o1.w = (v1.w - mu) * rs;
        *(float4*)&ln_sh[row][l32 * 8] = o0;
        *(float4*)&ln_sh[row][l32 * 8 + 4] = o1;
    }
    __syncthreads();

    const int n = t & 127;
    const int kh = t >> 7;
    float acc[8] = {0.f, 0.f, 0.f, 0.f, 0.f, 0.f, 0.f, 0.f};
#pragma unroll 2
    for (int c = 0; c < 32; ++c) {
        const int kc = kh * 128 + c * 4;
        float w0 = W[(kc + 0) * 128 + n];
        float w1 = W[(kc + 1) * 128 + n];
        float w2 = W[(kc + 2) * 128 + n];
        float w3 = W[(kc + 3) * 128 + n];
#pragma unroll
        for (int r = 0; r < 8; ++r) {
            float4 l4 = *(const float4*)&ln_sh[r][kc];
            acc[r] += l4.x * w0 + l4.y * w1 + l4.z * w2 + l4.w * w3;
        }
    }
    if (kh == 1) {
#pragma unroll
        for (int r = 0; r < 8; ++r) red_sh[n][r] = acc[r];
    }
    __syncthreads();
    if (kh == 0) {
#pragma unroll
        for (int r = 0; r < 8; ++r)
            proj[mat * 65536 + (i0 + r) * 128 + n] = acc[r] + red_sh[n][r];
    }
}

// ---------- kB: compacted i,j; dual-accumulator MFMA; dbuf staging ----------
#define KB_TI 4
__global__ __launch_bounds__(256) void kB(
    const float* __restrict__ pair, const int* __restrict__ act,
    const float* __restrict__ Wg, const float* __restrict__ Wv,
    const float* __restrict__ lg, const float* __restrict__ lv,
    const float* __restrict__ rg, const float* __restrict__ rv,
    float* __restrict__ left, float* __restrict__ right) {
    __shared__ __bf16 A_sh[2][32][72];
    __shared__ int ji_sh[32];
    __shared__ int ii_sh[KB_TI];

    const int cnt = act[0];
    const int j0 = blockIdx.x * 32;
    const int ibase = blockIdx.y * KB_TI;
    if (j0 >= cnt || ibase >= cnt) return;
    const int nact = min(KB_TI, cnt - ibase);

    const int t = threadIdx.x;
    const int lane = t & 63;
    const int w = t >> 6;
    const int c = lane & 31;
    const int half = lane >> 5;
    const int n = w * 32 + c;

    if (t < 32) ji_sh[t] = act[1 + min(j0 + t, cnt - 1)];
    if (t >= 64 && t < 64 + KB_TI) ii_sh[t - 64] = act[1 + min(ibase + (t - 64), cnt - 1)];
    __syncthreads();

    bf16x8 bg[4], bv[4];
#pragma unroll
    for (int kt = 0; kt < 4; ++kt) {
        bf16x8 vg, vv;
#pragma unroll
        for (int e = 0; e < 8; ++e) {
            int kr = kt * 16 + half * 8 + e;
            vg[e] = (__bf16)Wg[kr * 128 + n];
            vv[e] = (__bf16)Wv[kr * 128 + n];
        }
        bg[kt] = vg; bv[kt] = vv;
    }

    float lvr[16], rgr[16];
    unsigned jmask = 0;
#pragma unroll
    for (int r = 0; r < 16; ++r) {
        int m = 4 * half + (r & 3) + 8 * (r >> 2);
        int j = ji_sh[m];
        lvr[r] = lv[j * 128 + n];
        rgr[r] = rg[j * 128 + n];
        if (j0 + m < cnt) jmask |= (1u << r);
    }

    const int srow = t >> 3;
    const int kseg = (t & 7) * 8;
    float4 p0, p1;
    float plg, prv;
    {
        int iF = ii_sh[0];
        const float* src = pair + ((size_t)iF * 512 + ji_sh[srow]) * 64 + kseg;
        p0 = *(const float4*)src;
        p1 = *(const float4*)(src + 4);
        plg = lg[iF * 128 + n];
        prv = rv[iF * 128 + n];
    }

    auto lnwrite = [&](int buf) {
        float s = (p0.x + p0.y) + (p0.z + p0.w) + (p1.x + p1.y) + (p1.z + p1.w);
        float ss = p0.x * p0.x + p0.y * p0.y + p0.z * p0.z + p0.w * p0.w +
                   p1.x * p1.x + p1.y * p1.y + p1.z * p1.z + p1.w * p1.w;
        s += __shfl_xor(s, 1); ss += __shfl_xor(ss, 1);
        s += __shfl_xor(s, 2); ss += __shfl_xor(ss, 2);
        s += __shfl_xor(s, 4); ss += __shfl_xor(ss, 4);
        float mu = s * (1.f / 64.f);
        float rs = rsqrtf(ss * (1.f / 64.f) - mu * mu + LN_EPS);
        bf16x8 o;
        o[0] = (__bf16)((p0.x - mu) * rs); o[1] = (__bf16)((p0.y - mu) * rs);
        o[2] = (__bf16)((p0.z - mu) * rs); o[3] = (__bf16)((p0.w - mu) * rs);
        o[4] = (__bf16)((p1.x - mu) * rs); o[5] = (__bf16)((p1.y - mu) * rs);
        o[6] = (__bf16)((p1.z - mu) * rs); o[7] = (__bf16)((p1.w - mu) * rs);
        *(bf16x8*)&A_sh[buf][srow][kseg] = o;
    };
    lnwrite(0);
    __syncthreads();

    float racc[16];
#pragma unroll
    for (int r = 0; r < 16; ++r) racc[r] = 0.f;

    for (int ii = 0; ii < nact; ++ii) {
        const int i = ii_sh[ii];
        const float lgi = plg;
        const float rvi = prv;
        if (ii + 1 < nact) {
            int iF = ii_sh[ii + 1];
            const float* src = pair + ((size_t)iF * 512 + ji_sh[srow]) * 64 + kseg;
            p0 = *(const float4*)src;
            p1 = *(const float4*)(src + 4);
            plg = lg[iF * 128 + n];
            prv = rv[iF * 128 + n];
        }

        f32x16 ag = {}; f32x16 av = {};
#pragma unroll
        for (int kt = 0; kt < 4; ++kt) {
            bf16x8 af = *(const bf16x8*)&A_sh[ii & 1][c][kt * 16 + half * 8];
            ag = __builtin_amdgcn_mfma_f32_32x32x16_bf16(af, bg[kt], ag, 0, 0, 0);
            av = __builtin_amdgcn_mfma_f32_32x32x16_bf16(af, bv[kt], av, 0, 0, 0);
        }

        float lsum = 0.f;
#pragma unroll
        for (int r = 0; r < 16; ++r) {
            float pg = ag[r], pv = av[r];
            float lres = gelu_f(lgi + pg) * (lvr[r] + pv);
            float rres = gelu_f(rgr[r] + pg) * (rvi + pv);
            lsum += ((jmask >> r) & 1) ? lres : 0.f;
            racc[r] += rres;
        }
        float tot = lsum + __shfl_xor(lsum, 32);
        if (lane < 32) atomicAdd(&left[i * 128 + n], tot);

        if (ii + 1 < nact) lnwrite((ii + 1) & 1);
        __syncthreads();
    }

#pragma unroll
    for (int r = 0; r < 16; ++r) {
        if ((jmask >> r) & 1) {
            int m = 4 * half + (r & 3) + 8 * (r >> 2);
            atomicAdd(&right[ji_sh[m] * 128 + n], racc[r]);
        }
    }
}

// ---------- kD: kD1 (A/B proj + colsums) and kD2 (C = L@R^T, fused LN-stat precompute) ----------
__global__ __launch_bounds__(256) void kD(
    const float* __restrict__ left, const float* __restrict__ right,
    const float* __restrict__ W_out,
    float* __restrict__ Aw, float* __restrict__ Bw,
    float* __restrict__ rsrm, float* __restrict__ cs) {
    const int bx = blockIdx.x;
    const int t = threadIdx.x;
    if (bx < 256) {   // --- kD2 tile ---
        __shared__ float l_sh[32][68];
        __shared__ float r_sh[32][68];
        const int tx = t & 15, ty = t >> 4;
        const int i0 = (bx & 15) * 32, j0 = (bx >> 4) * 32;
        float acc00 = 0.f, acc01 = 0.f, acc10 = 0.f, acc11 = 0.f;
        float sL0 = 0.f, ssL0 = 0.f, sL1 = 0.f, ssL1 = 0.f;
        float sR0 = 0.f, ssR0 = 0.f, sR1 = 0.f, ssR1 = 0.f;
        for (int kc = 0; kc < 128; kc += 64) {
            __syncthreads();
#pragma unroll
            for (int u = 0; u < 2; ++u) {
                int fi = t + u * 256;
                int row = fi >> 4, kq = (fi & 15) * 4;
                float4 lv4 = *(const float4*)(left + (i0 + row) * 128 + kc + kq);
                float4 rv4 = *(const float4*)(right + (j0 + row) * 128 + kc + kq);
                *(float4*)&l_sh[row][kq] = lv4;
                *(float4*)&r_sh[row][kq] = rv4;
            }
            __syncthreads();
#pragma unroll
            for (int k4 = 0; k4 < 64; k4 += 4) {
                float4 l0 = *(const float4*)&l_sh[ty * 2 + 0][k4];
                float4 l1 = *(const float4*)&l_sh[ty * 2 + 1][k4];
                float4 r0 = *(const float4*)&r_sh[tx * 2 + 0][k4];
                float4 r1 = *(const float4*)&r_sh[tx * 2 + 1][k4];
                acc00 += l0.x * r0.x + l0.y * r0.y + l0.z * r0.z + l0.w * r0.w;
                acc01 += l0.x * r1.x + l0.y * r1.y + l0.z * r1.z + l0.w * r1.w;
                acc10 += l1.x * r0.x + l1.y * r0.y + l1.z * r0.z + l1.w * r0.w;
                acc11 += l1.x * r1.x + l1.y * r1.y + l1.z * r1.z + l1.w * r1.w;
                sL0 += (l0.x + l0.y) + (l0.z + l0.w);
                ssL0 += l0.x * l0.x + l0.y * l0.y + l0.z * l0.z + l0.w * l0.w;
                sL1 += (l1.x + l1.y) + (l1.z + l1.w);
                ssL1 += l1.x * l1.x + l1.y * l1.y + l1.z * l1.z + l1.w * l1.w;
                sR0 += (r0.x + r0.y) + (r0.z + r0.w);
                ssR0 += r0.x * r0.x + r0.y * r0.y + r0.z * r0.z + r0.w * r0.w;
                sR1 += (r1.x + r1.y) + (r1.z + r1.w);
                ssR1 += r1.x * r1.x + r1.y * r1.y + r1.z * r1.z + r1.w * r1.w;
            }
        }
        {
            float sLa[2] = {sL0, sL1}, ssLa[2] = {ssL0, ssL1};
            float sRb[2] = {sR0, sR1}, ssRb[2] = {ssR0, ssR1};
            float accv[2][2] = {{acc00, acc01}, {acc10, acc11}};
#pragma unroll
            for (int a = 0; a < 2; ++a) {
#pragma unroll
                for (int b = 0; b < 2; ++b) {
                    float mu = (sLa[a] + sRb[b]) * (1.f / 128.f);
                    float var = fmaf(-mu, mu,
                                     (ssLa[a] + 2.f * accv[a][b] + ssRb[b]) * (1.f / 128.f));
                    float rs = rsqrtf(var + LN_EPS);
                    size_t idx = (size_t)(i0 + ty * 2 + a) * 512 + (j0 + tx * 2 + b);
                    float2 v; v.x = rs; v.y = rs * mu;
                    ((float2*)rsrm)[idx] = v;
                }
            }
        }
    } else {          // --- kD1: two (r, which) jobs per block ---
        const int id = bx - 256;            // 0..511
        const int which = id >> 8;
        const int sub = t >> 7;
        const int tt = t & 127;
        const int r = (id & 255) * 2 + sub;
        const float* src = which ? right : left;
        __shared__ float row_sh[2][128];
        row_sh[sub][tt] = src[r * 128 + tt];
        __syncthreads();
        if (tt < 64) {
            float a = 0.f;
            const float* W2 = W_out + 64 * 64;
#pragma unroll 8
            for (int m = 0; m < 128; ++m) a += row_sh[sub][m] * W2[m * 64 + tt];
            (which ? Bw : Aw)[r * 64 + tt] = a;
        }
        if (id == 0 && t < 64) {
            float c0 = 0.f, c1 = 0.f;
            for (int k = 0; k < 64; ++k) c0 += W_out[k * 64 + t];
            for (int m = 0; m < 128; ++m) c1 += W_out[(64 + m) * 64 + t];
            cs[t] = c0;
            cs[64 + t] = c1;
        }
    }
}

// ---------- kC: global_load_lds double-buffered pair staging ----------
// R8/R9 showed kC pinned at ~40us with register double-buffer (va/vb = 64 VGPR,
// only 512B in flight per wave, idle between prefetch windows). Now: per-body
// 64x64 f32 pair tile staged to LDS via global_load_lds width=16 (no VGPR
// round-trip, loads queue in HW while MFMA runs). XOR-swizzle (kb ^ (row&7)<<4)
// applied on the GLOBAL source + on each 16B ds_read (linear LDS dest, rule #21)
// to break the 256B-row-stride bank conflict.
__global__ __launch_bounds__(256) void kC(
    const float* __restrict__ pair, const float* __restrict__ Wout,
    const float* __restrict__ Aw, const float* __restrict__ Bw,
    const float* __restrict__ rsrm,
    const float* __restrict__ cs, float* __restrict__ out) {
    __shared__ float tile[2][64][64];     // 32 KB, double-buffered pair tiles
    __shared__ float2 rsrm_sh[4][64];     // 2 KB
    const int t = threadIdx.x;
    const int lane = t & 63;
    const int w = t >> 6;
    const int c = lane & 31;
    const int half = lane >> 5;
    const int i0 = blockIdx.x * 4;
    const int j0 = blockIdx.y * 64;
    const int mt = w & 1;
    const int nt = w >> 1;
    const int n = nt * 32 + c;

    // stage body ii's 64x64 tile: wave w covers rows w*16..w*16+15, 4 instrs
    auto stage = [&](int ii) {
        float* dst0 = &tile[ii & 1][0][0];
        const size_t gbase = ((size_t)(i0 + ii) * 512 + j0) * 64;
#pragma unroll
        for (int q = 0; q < 4; ++q) {
            int row = w * 16 + q * 4 + (lane >> 4);
            int gkb = ((lane & 15) << 4) ^ ((row & 7) << 4);   // inverse-swz source
            gload_lds16(pair + gbase + row * 64 + (gkb >> 2),
                        dst0 + (w * 16 + q * 4) * 64);
        }
    };

    stage(0);
    rsrm_sh[t >> 6][t & 63] =
        ((const float2*)rsrm)[(size_t)(i0 + (t >> 6)) * 512 + j0 + (t & 63)];

    bf16x8 bo[4];                                 // i-invariant: Wout fragments
#pragma unroll
    for (int kt = 0; kt < 4; ++kt) {
        bf16x8 bb;
#pragma unroll
        for (int e = 0; e < 8; ++e)
            bb[e] = (__bf16)Wout[(kt * 16 + half * 8 + e) * 64 + n];
        bo[kt] = bb;
    }
    float Bv[16];                                 // i-invariant: Bw values
#pragma unroll
    for (int r = 0; r < 16; ++r) {
        int jp = j0 + mt * 32 + 4 * half + (r & 3) + 8 * (r >> 2);
        Bv[r] = Bw[jp * 64 + n];
    }
    float Awr[4];
#pragma unroll
    for (int u = 0; u < 4; ++u) Awr[u] = Aw[(i0 + u) * 64 + n];
    const float cs1n = cs[64 + n];

    const int jl_me = mt * 32 + c;                // lane's own pair row in tile
    const int sw = (jl_me & 7) << 4;              // read-side swizzle (bytes)
    const char* rowp = (const char*)&tile[0][jl_me][0];
    const int tstride = (int)sizeof(float) * 64 * 64;   // bytes between buffers

    __syncthreads();                              // tile0 + rsrm_sh ready

    auto body = [&](int ii) {
        if (ii < 3) stage(ii + 1);                // async into buf^1

        // read own row (32 floats, swizzled 16B reads; k-order preserved)
        const char* rp = rowp + (ii & 1) * tstride;
        float4 f[8];
#pragma unroll
        for (int kt = 0; kt < 4; ++kt) {
            int K = half * 32 + kt * 64;          // wanted k-byte base
            f[2 * kt] = *(const float4*)(rp + (K ^ sw));
            f[2 * kt + 1] = *(const float4*)(rp + ((K + 16) ^ sw));
        }

        float s = 0.f, ss = 0.f;
#pragma unroll
        for (int u = 0; u < 8; ++u) {
            s += (f[u].x + f[u].y) + (f[u].z + f[u].w);
            ss += f[u].x * f[u].x + f[u].y * f[u].y +
                  f[u].z * f[u].z + f[u].w * f[u].w;
        }
        s += __shfl_xor(s, 32);
        ss += __shfl_xor(ss, 32);
        float mu = s * (1.f / 64.f);
        float rs = rsqrtf(ss * (1.f / 64.f) - mu * mu + LN_EPS);
        float nmr = -mu * rs;

        f32x16 acc = {};
#pragma unroll
        for (int kt = 0; kt < 4; ++kt) {
            bf16x8 af;
#pragma unroll
            for (int u = 0; u < 2; ++u) {
                float4 vv = f[2 * kt + u];
                af[u * 4 + 0] = (__bf16)fmaf(vv.x, rs, nmr);
                af[u * 4 + 1] = (__bf16)fmaf(vv.y, rs, nmr);
                af[u * 4 + 2] = (__bf16)fmaf(vv.z, rs, nmr);
                af[u * 4 + 3] = (__bf16)fmaf(vv.w, rs, nmr);
            }
            acc = __builtin_amdgcn_mfma_f32_32x32x16_bf16(af, bo[kt], acc, 0, 0, 0);
        }

        const int i = i0 + ii;
        const float A_in = Awr[ii];
#pragma unroll
        for (int r = 0; r < 16; ++r) {
            int jl = mt * 32 + 4 * half + (r & 3) + 8 * (r >> 2);
            float2 rr = rsrm_sh[ii][jl];
            out[((size_t)i * 512 + j0 + jl) * 64 + n] =
                fmaf(rr.x, A_in + Bv[r], fmaf(-rr.y, cs1n, acc[r]));
        }
        __syncthreads();                          // stage(ii+1) done; buf reusable
    };
    body(0);
    body(1);
    body(2);
    body(3);
}

extern "C" void kernel_launch(void* const* d_in, const int* in_sizes, int n_in,
                              void* d_out, int out_size, void* d_ws, size_t ws_size,
                              hipStream_t stream) {
    const float* loc  = (const float*)d_in[0];
    const float* pair = (const float*)d_in[1];
    const int*   mask = (const int*)d_in[2];
    const float* Wpg  = (const float*)d_in[3];
    const float* Wpv  = (const float*)d_in[4];
    const float* Wlg  = (const float*)d_in[5];
    const float* Wlv  = (const float*)d_in[6];
    const float* Wrg  = (const float*)d_in[7];
    const float* Wrv  = (const float*)d_in[8];
    const float* Wout = (const float*)d_in[9];
    float* out = (float*)d_out;
    float* ws = (float*)d_ws;

    float* proj   = ws;             // lg lv rg rv
    float* left   = ws + 262144;
    float* right  = ws + 327680;
    float* Aw     = ws + 393216;
    float* Bw     = ws + 425984;
    float* rsrm   = ws + 458752;    // float2[512*512]: {rs_s, rs_s*mu_s}
    float* cs     = ws + 983040;
    int*   act    = (int*)(ws + 983168);

    kA<<<dim3(65, 4), 256, 0, stream>>>(loc, Wlg, Wlv, Wrg, Wrv, proj,
                                        mask, act, left, right);
    kB<<<dim3(16, 128), 256, 0, stream>>>(pair, act, Wpg, Wpv,
                                          proj, proj + 65536, proj + 131072,
                                          proj + 196608, left, right);
    kD<<<768, 256, 0, stream>>>(left, right, Wout, Aw, Bw, rsrm, cs);
    kC<<<dim3(128, 8), 256, 0, stream>>>(pair, Wout, Aw, Bw, rsrm, cs, out);
}